// Round 14
// baseline (522.997 us; speedup 1.0000x reference)
//
#include <hip/hip_runtime.h>
#include <cmath>

#define NN 1024
#define BC 128
#define LS 24

typedef unsigned short u16;
typedef __attribute__((ext_vector_type(4))) float f32x4;
typedef __attribute__((ext_vector_type(8))) short bf16x8;
typedef __attribute__((ext_vector_type(4))) unsigned short u16x4;
typedef __attribute__((ext_vector_type(8))) unsigned short u16x8;

typedef __attribute__((address_space(1))) const void* as1cv;
typedef __attribute__((address_space(3))) void* as3v;

#define GLD16(gp, lp) __builtin_amdgcn_global_load_lds((as1cv)(gp), (as3v)(lp), 16, 0, 0)

__device__ __forceinline__ float sigf(float x){ return 1.0f/(1.0f+expf(-x)); }

__device__ __forceinline__ u16 f2b(float x){
  union { float f; unsigned u; } v; v.f = x;
  unsigned r = v.u + 0x7FFFu + ((v.u >> 16) & 1u);
  return (u16)(r >> 16);
}
__device__ __forceinline__ float b2f(u16 b){
  union { unsigned u; float f; } v; v.u = ((unsigned)b) << 16;
  return v.f;
}

// ---------------- fused preprocessing ----------------
// blocks [0,128): transpose (4 idx/thread, u16x4 stores); [128,192): colsum1;
// [192,208): packbias; [208,...): pack x8
__global__ void k_prep(const float* __restrict__ inputs, const float* __restrict__ adj,
                       const float* __restrict__ Wf, const float* __restrict__ Wi,
                       const float* __restrict__ Wo, const float* __restrict__ Wc,
                       const float* __restrict__ rWf, const float* __restrict__ rWi,
                       const float* __restrict__ rWo, const float* __restrict__ rWc,
                       const float* __restrict__ bf_, const float* __restrict__ bi_,
                       const float* __restrict__ bo_, const float* __restrict__ bc_,
                       const float* __restrict__ rbf, const float* __restrict__ rbi,
                       const float* __restrict__ rbo, const float* __restrict__ rbc,
                       u16* __restrict__ Xb, float* __restrict__ csum,
                       u16* __restrict__ Wgxb, u16* __restrict__ WgHp,
                       u16* __restrict__ rWgxb, u16* __restrict__ rWgHp,
                       float* __restrict__ bgcat){
  int b = blockIdx.x, tid = threadIdx.x;
  if (b < 128){
    int base = b*1024 + tid*4;                   // 4 consecutive idx per thread
    #pragma unroll
    for (int q = 0; q < 6; ++q){                 // t-group q: t = q*4..q*4+3
      float4 v[4];
      #pragma unroll
      for (int i = 0; i < 4; ++i)
        v[i] = *(const float4*)(inputs + (size_t)(base+i)*LS + q*4);
      #pragma unroll
      for (int tt = 0; tt < 4; ++tt){
        float e0 = (tt==0)?v[0].x:(tt==1)?v[0].y:(tt==2)?v[0].z:v[0].w;
        float e1 = (tt==0)?v[1].x:(tt==1)?v[1].y:(tt==2)?v[1].z:v[1].w;
        float e2 = (tt==0)?v[2].x:(tt==1)?v[2].y:(tt==2)?v[2].z:v[2].w;
        float e3 = (tt==0)?v[3].x:(tt==1)?v[3].y:(tt==2)?v[3].z:v[3].w;
        u16x4 o = { f2b(e0), f2b(e1), f2b(e2), f2b(e3) };
        *(u16x4*)(Xb + (size_t)(q*4+tt)*BC*NN + base) = o;
      }
    }
  } else if (b < 192){
    int bb = b - 128;
    for (int j = tid; j < 1024; j += 256){
      float s = 0.f;
      for (int i = 0; i < 16; ++i) s += adj[(size_t)(bb*16+i)*1024 + j];
      csum[(size_t)bb*1024 + j] = s;
    }
  } else if (b < 208){
    int idx = (b-192)*256 + tid;                 // 4096
    int seg = idx >> 10, j = idx & 1023;
    bgcat[idx]      = (seg==0?bf_: seg==1?bi_: seg==2?bo_:bc_)[j];
    bgcat[4096+idx] = (seg==0?rbf: seg==1?rbi: seg==2?rbo:rbc)[j];
  } else {
    int idx = (b-208)*256 + tid;                 // 8-element groups
    if (idx < 2097152){                          // main W: 4096 rows x 512 groups
      int kg = idx & 511, r = idx >> 9;
      int seg = r >> 10, j = r & 1023;
      const float* W = (seg==0?Wf: seg==1?Wi: seg==2?Wo:Wc) + (size_t)j*4096 + kg*8;
      float4 a = *(const float4*)W;
      float4 c = *(const float4*)(W + 4);
      u16x8 o = { f2b(a.x), f2b(a.y), f2b(a.z), f2b(a.w),
                  f2b(c.x), f2b(c.y), f2b(c.z), f2b(c.w) };
      if (kg < 384) *(u16x8*)(Wgxb + (size_t)r*3072 + kg*8) = o;
      else {
        int p = (j>>3)*32 + seg*8 + (j&7);
        *(u16x8*)(WgHp + (size_t)p*1024 + (kg*8 - 3072)) = o;
      }
    } else {
      int g2 = idx - 2097152;                    // rW: 4096 rows x 256 groups
      int kg = g2 & 255, r = g2 >> 8;
      int seg = r >> 10, j = r & 1023;
      const float* W = (seg==0?rWf: seg==1?rWi: seg==2?rWo:rWc) + (size_t)j*2048 + kg*8;
      float4 a = *(const float4*)W;
      float4 c = *(const float4*)(W + 4);
      u16x8 o = { f2b(a.x), f2b(a.y), f2b(a.z), f2b(a.w),
                  f2b(c.x), f2b(c.y), f2b(c.z), f2b(c.w) };
      if (kg < 128) *(u16x8*)(rWgxb + (size_t)r*1024 + kg*8) = o;
      else {
        int p = (j>>3)*32 + seg*8 + (j&7);
        *(u16x8*)(rWgHp + (size_t)p*1024 + (kg*8 - 1024)) = o;
      }
    }
  }
}

// fused: tmp from csum partials (per block-row) + A1b + anormT
__global__ void k_anormT(const float* __restrict__ adj, const float* __restrict__ csum,
                         u16* __restrict__ A1b, u16* __restrict__ anormT){
  __shared__ u16 t[64][65];
  __shared__ float tmps[64];
  int bi = blockIdx.y*64, bj = blockIdx.x*64;
  // tmp[bi+r] = sum_b csum[b][bi+r]; 64 rows x 64 partials, 256 threads
  if (threadIdx.x < 64){
    int r = threadIdx.x;
    float s = 0.f;
    for (int p = 0; p < 64; ++p) s += csum[(size_t)p*1024 + bi + r];
    tmps[r] = (s == 0.f) ? 1e-5f : s;
  }
  __syncthreads();
  for (int e = threadIdx.x; e < 4096; e += 256){
    int r = e >> 6, cc = e & 63;
    float v = tmps[r]*adj[(size_t)(bi+r)*1024 + bj+cc];
    A1b[(size_t)(bi+r)*1024 + bj+cc] = f2b(fminf(v, 1.f));
    t[r][cc] = f2b(v);
  }
  __syncthreads();
  for (int e = threadIdx.x; e < 4096; e += 256){
    int r = e >> 6, cc = e & 63;
    anormT[(size_t)(bj+r)*1024 + bi+cc] = t[cc][r];
  }
}

// merged: blocks [0,1024) = nbr rows; [1024,1792) = effT tiles
__global__ void k_nbreff(const u16* __restrict__ A3b, const float* __restrict__ nw,
                         float* __restrict__ nbr,
                         const u16* __restrict__ Ap, const float* __restrict__ gcw,
                         u16* __restrict__ effb, u16* __restrict__ effbT){
  __shared__ float red[256];
  __shared__ u16 t[64][65];
  int b = blockIdx.x, tid = threadIdx.x;
  if (b < 1024){
    int row = b;
    float s = 0.f;
    for (int j = tid; j < 1024; j += 256)
      s += b2f(A3b[(size_t)row*1024 + j])*nw[j];
    red[tid] = s; __syncthreads();
    for (int st = 128; st > 0; st >>= 1){
      if (tid < st) red[tid] += red[tid+st];
      __syncthreads();
    }
    if (tid == 0) nbr[row] = red[0];
  } else {
    int e2 = b - 1024;
    int bj = (e2 & 15)*64, bi = (e2 >> 4)*64;   // bi over 3072, bj over 1024
    for (int e = tid; e < 4096; e += 256){
      int r = e >> 6, cc = e & 63;
      size_t idx = (size_t)(bi+r)*1024 + bj+cc;
      u16 v = f2b(b2f(Ap[idx]) * gcw[idx]);
      effb[idx] = v;
      t[r][cc] = v;
    }
    __syncthreads();
    for (int e = tid; e < 4096; e += 256){
      int r = e >> 6, cc = e & 63;
      effbT[(size_t)(bj+r)*3072 + bi+cc] = t[cc][r];
    }
  }
}

// ---------------- 64x64 pre tile (K=1024, BK=128), shared by prologue and k_step ----------------
__device__ __forceinline__ void pre_tile64(int g, const u16* __restrict__ Xs,
                                           const u16* __restrict__ Bcat,
                                           const float* __restrict__ bgcat,
                                           u16* __restrict__ outs, u16* lds)
{
  u16* ldsA = lds;            // 64*128
  u16* ldsB = lds + 8192;     // 64*128
  const int tid  = threadIdx.x;
  const int lane = tid & 63;
  const int w    = tid >> 6;
  const int wr   = (w >> 1) * 32;
  const int wc   = (w & 1) * 32;
  const int rh = g >> 7, cp = g & 127;
  const u16* A = Xs + (size_t)rh*64*1024;
  const u16* B = Bcat + (size_t)cp*64*1024;
  f32x4 acc[2][2] = {};

  const int r4  = lane >> 4;
  const int g16 = lane & 15;
  for (int k0 = 0; k0 < 1024; k0 += 128){
    #pragma unroll
    for (int c = 0; c < 4; ++c){
      int rowb = w*16 + c*4;
      int row = rowb + r4;
      int srcg = (g16 & 8) | ((g16 & 7) ^ (row & 7));
      GLD16(A + (size_t)row*1024 + k0 + srcg*8, &ldsA[rowb*128]);
      GLD16(B + (size_t)row*1024 + k0 + srcg*8, &ldsB[rowb*128]);
    }
    __syncthreads();
    #pragma unroll
    for (int kk = 0; kk < 4; ++kk){
      int idx = kk*4 + (lane >> 4);
      bf16x8 af[2], bfr[2];
      #pragma unroll
      for (int mi = 0; mi < 2; ++mi){
        int row = wr + mi*16 + (lane & 15);
        int pa = (idx & 8) | ((idx & 7) ^ (row & 7));
        af[mi] = *(const bf16x8*)&ldsA[row*128 + pa*8];
      }
      #pragma unroll
      for (int ni = 0; ni < 2; ++ni){
        int row = wc + ni*16 + (lane & 15);
        int pb = (idx & 8) | ((idx & 7) ^ (row & 7));
        bfr[ni] = *(const bf16x8*)&ldsB[row*128 + pb*8];
      }
      #pragma unroll
      for (int mi = 0; mi < 2; ++mi)
        #pragma unroll
        for (int ni = 0; ni < 2; ++ni)
          acc[mi][ni] = __builtin_amdgcn_mfma_f32_16x16x32_bf16(af[mi], bfr[ni], acc[mi][ni], 0, 0, 0);
    }
    __syncthreads();
  }
  #pragma unroll
  for (int mi = 0; mi < 2; ++mi){
    #pragma unroll
    for (int ni = 0; ni < 2; ++ni){
      int col = cp*64 + wc + ni*16 + (lane & 15);
      float bv = bgcat[col];
      #pragma unroll
      for (int q = 0; q < 4; ++q){
        int row = rh*64 + wr + mi*16 + (lane >> 4)*4 + q;
        outs[(size_t)row*8192 + col] = f2b(acc[mi][ni][q] + bv);
      }
    }
  }
}

// prologue: pre slice 0 (256 blocks)
__global__ __launch_bounds__(256) void k_pre0(
    const u16* __restrict__ Xs, const u16* __restrict__ Bcat,
    const float* __restrict__ bgcat, u16* __restrict__ outs)
{
  __shared__ u16 lds[16384];
  pre_tile64(blockIdx.x, Xs, Bcat, bgcat, outs, lds);
}

// ---------------- 64x64-tile NT GEMM, BK=128 (32 KB LDS) ----------------
__global__ __launch_bounds__(256) void k_mfma64(
    const u16* __restrict__ Ag, const u16* __restrict__ Bg, int K,
    int clamp1, int swz, u16* __restrict__ outb, int ldc)
{
  __shared__ u16 ldsA[64*128];   // 16 KB
  __shared__ u16 ldsB[64*128];   // 16 KB
  const int tid  = threadIdx.x;
  const int lane = tid & 63;
  const int w    = tid >> 6;
  const int wr   = (w >> 1) * 32;
  const int wc   = (w & 1) * 32;
  int bx = blockIdx.x, by = blockIdx.y;
  if (swz){  // valid for grid (16,64): each XCD owns an 8-panel A-stripe (3 MB, L2-fit)
    int id = by*16 + bx;
    by = (id & 7)*8 + ((id >> 3) & 7);   // [0,64)
    bx = id >> 6;                        // [0,16)
  }
  const u16* A = Ag + (size_t)by*64*K;
  const u16* B = Bg + (size_t)bx*64*K;
  f32x4 acc[2][2] = {};

  const int r4  = lane >> 4;
  const int g16 = lane & 15;
  for (int k0 = 0; k0 < K; k0 += 128){
    #pragma unroll
    for (int c = 0; c < 4; ++c){
      int rowb = w*16 + c*4;
      int row = rowb + r4;
      int srcg = (g16 & 8) | ((g16 & 7) ^ (row & 7));
      GLD16(A + (size_t)row*K + k0 + srcg*8, &ldsA[rowb*128]);
      GLD16(B + (size_t)row*K + k0 + srcg*8, &ldsB[rowb*128]);
    }
    __syncthreads();
    #pragma unroll
    for (int kk = 0; kk < 4; ++kk){
      int idx = kk*4 + (lane >> 4);
      bf16x8 af[2], bfr[2];
      #pragma unroll
      for (int mi = 0; mi < 2; ++mi){
        int row = wr + mi*16 + (lane & 15);
        int pa = (idx & 8) | ((idx & 7) ^ (row & 7));
        af[mi] = *(const bf16x8*)&ldsA[row*128 + pa*8];
      }
      #pragma unroll
      for (int ni = 0; ni < 2; ++ni){
        int row = wc + ni*16 + (lane & 15);
        int pb = (idx & 8) | ((idx & 7) ^ (row & 7));
        bfr[ni] = *(const bf16x8*)&ldsB[row*128 + pb*8];
      }
      #pragma unroll
      for (int mi = 0; mi < 2; ++mi)
        #pragma unroll
        for (int ni = 0; ni < 2; ++ni)
          acc[mi][ni] = __builtin_amdgcn_mfma_f32_16x16x32_bf16(af[mi], bfr[ni], acc[mi][ni], 0, 0, 0);
    }
    __syncthreads();
  }
  #pragma unroll
  for (int mi = 0; mi < 2; ++mi){
    #pragma unroll
    for (int ni = 0; ni < 2; ++ni){
      int col = bx*64 + wc + ni*16 + (lane & 15);
      #pragma unroll
      for (int q = 0; q < 4; ++q){
        int row = by*64 + wr + mi*16 + (lane >> 4)*4 + q;
        float v = acc[mi][ni][q];
        if (clamp1) v = fminf(v, 1.f);
        outb[(size_t)row*ldc + col] = f2b(v);
      }
    }
  }
}

// ---------------- fused per-step kernel: 512 LSTM blocks + 256 pre-slice(t+1) blocks ----------
__global__ __launch_bounds__(256) void k_step(
    const u16* __restrict__ WgHp, const u16* __restrict__ rWgHp,
    const u16* __restrict__ pre_t,           // [BC][8192] bf16; job*4096 col offset
    const u16* __restrict__ Xb_next, const u16* __restrict__ Bcat,
    const float* __restrict__ bgcat, u16* __restrict__ pre_next, int do_pre,
    const float* __restrict__ nbrv,
    u16* __restrict__ Hb2, u16* __restrict__ rHb2,
    float* __restrict__ Cs, float* __restrict__ rCs,
    float* __restrict__ Hf, float* __restrict__ rHf,
    int ph, int last)
{
  __shared__ u16 lds[24576];   // 48 KB (LSTM); pre branch uses first 32 KB

  const int tid  = threadIdx.x;
  const int lane = tid & 63;
  const int w    = tid >> 6;          // 0..3
  const int bid  = blockIdx.x;

  if (bid >= 512){
    if (do_pre) pre_tile64(bid - 512, Xb_next, Bcat, bgcat, pre_next, lds);
    return;
  }

  u16* ldsA0 = lds;              // [2][64*128]
  u16* ldsB0 = lds + 16384;      // [2][32*128]

  const int job  = bid >> 8;
  const int rem  = bid & 255;
  const int s    = rem >> 1;
  const int r0   = (rem & 1) * 64;

  const u16* Bp   = (job ? rWgHp : WgHp) + (size_t)s*32*1024;
  const u16* Ab   = (job ? rHb2 : Hb2) + (size_t)ph*BC*NN + (size_t)r0*NN;
  const u16* pret = pre_t + (size_t)job*4096;
  u16* Hnext  = (job ? rHb2 : Hb2) + (size_t)(ph^1)*BC*NN;
  float* Csb  = job ? rCs : Cs;
  float* Hfin = job ? rHf : Hf;

  const int r4  = lane >> 4;           // 0..3 row offset within 1KB issue
  const int g16 = lane & 15;           // 16B group within 256B row

  auto STAGE = [&](int ck, int buf){
    int k0 = ck*128;
    #pragma unroll
    for (int c = 0; c < 4; ++c){
      int rowb = w*16 + c*4;
      int row = rowb + r4;
      int srcg = (g16 & 8) | ((g16 & 7) ^ (row & 7));
      GLD16(Ab + (size_t)row*1024 + k0 + srcg*8, &ldsA0[buf*8192 + rowb*128]);
    }
    #pragma unroll
    for (int c = 0; c < 2; ++c){
      int rowb = w*8 + c*4;
      int row = rowb + r4;
      int srcg = (g16 & 8) | ((g16 & 7) ^ (row & 7));
      GLD16(Bp + (size_t)row*1024 + k0 + srcg*8, &ldsB0[buf*4096 + rowb*128]);
    }
  };

  f32x4 acc[2] = {};
  STAGE(0, 0);
  #pragma unroll
  for (int t = 0; t < 8; ++t){
    const int cur = t & 1;
    if (t < 7){
      STAGE(t+1, cur^1);
      asm volatile("s_waitcnt vmcnt(6)" ::: "memory");
    } else {
      asm volatile("s_waitcnt vmcnt(0)" ::: "memory");
    }
    __builtin_amdgcn_sched_barrier(0);
    __builtin_amdgcn_s_barrier();
    #pragma unroll
    for (int kk = 0; kk < 4; ++kk){
      int idx = kk*4 + (lane >> 4);
      int rowa = w*16 + (lane & 15);
      int pa = (idx & 8) | ((idx & 7) ^ (rowa & 7));
      bf16x8 af = *(const bf16x8*)&ldsA0[cur*8192 + rowa*128 + pa*8];
      #pragma unroll
      for (int ni = 0; ni < 2; ++ni){
        int rowb2 = ni*16 + (lane & 15);
        int pb = (idx & 8) | ((idx & 7) ^ (rowb2 & 7));
        bf16x8 bv = *(const bf16x8*)&ldsB0[cur*4096 + rowb2*128 + pb*8];
        acc[ni] = __builtin_amdgcn_mfma_f32_16x16x32_bf16(af, bv, acc[ni], 0, 0, 0);
      }
    }
    __builtin_amdgcn_sched_barrier(0);
    __builtin_amdgcn_s_barrier();
  }

  // epilogue: + pre, gates via shfl_xor(8) (round-4/9/10/13 verified mapping)
  #pragma unroll
  for (int ni = 0; ni < 2; ++ni){
    int pcol = ni*16 + (lane & 15);
    int gcol = (pcol >> 3)*1024 + s*8 + (pcol & 7);
    #pragma unroll
    for (int q = 0; q < 4; ++q){
      int row = r0 + w*16 + (lane >> 4)*4 + q;
      acc[ni][q] += b2f(pret[(size_t)row*8192 + gcol]);
    }
  }
  const bool act = (lane & 15) < 8;
  const int  c   = lane & 7;
  const int  col = s*8 + c;
  float fac = 1.f;
  if (!job && act) fac = nbrv[col];
  #pragma unroll
  for (int q = 0; q < 4; ++q){
    float a0 = acc[0][q], a1 = acc[1][q];
    float p1 = __shfl_xor(a0, 8);   // seg1 (i-gate)
    float p3 = __shfl_xor(a1, 8);   // seg3 (Ct)
    if (act){
      int row = r0 + w*16 + (lane >> 4)*4 + q;
      float fg = sigf(a0), ig = sigf(p1), og = sigf(a1), ct = tanhf(p3);
      size_t cidx = (size_t)row*NN + col;
      float cs = fg*Csb[cidx]*fac + ig*ct;
      Csb[cidx] = cs;
      float h = og*tanhf(cs);
      Hnext[cidx] = f2b(h);
      if (last) Hfin[cidx] = h;
    }
  }
}

// ---------------- last-step statistics ----------------
__global__ void k_var1(const u16* __restrict__ Xl, const u16* __restrict__ gcl,
                       float* __restrict__ part){
  int ch = blockIdx.x & 1, seg = blockIdx.x >> 1;   // 64 blocks
  int tid = threadIdx.x;
  float s1=0.f,q1=0.f,s2=0.f,q2=0.f;
  for (int bb = 0; bb < 2; ++bb){
    int row = (seg*2+bb)*2 + ch;
    const u16* xr = Xl + (size_t)row*1024;
    for (int n = tid; n < 1024; n += 256){ float v = b2f(xr[n]); s1 += v; q1 += v*v; }
    const u16* gr = gcl + (size_t)row*3072;
    for (int n = tid; n < 3072; n += 256){ float v = b2f(gr[n]); s2 += v; q2 += v*v; }
  }
  __shared__ float red[256][4];
  red[tid][0]=s1; red[tid][1]=q1; red[tid][2]=s2; red[tid][3]=q2;
  __syncthreads();
  for (int st = 128; st > 0; st >>= 1){
    if (tid < st){ for (int z = 0; z < 4; ++z) red[tid][z] += red[tid+st][z]; }
    __syncthreads();
  }
  if (tid == 0){ for (int z = 0; z < 4; ++z) part[(size_t)blockIdx.x*4 + z] = red[0][z]; }
}

// fused var2 + pred + conv: one thread per (b,n), 256 blocks
__global__ void k_out(const float* __restrict__ H, const float* __restrict__ rH,
                      const float* __restrict__ part, const float* __restrict__ cptr,
                      const float* __restrict__ cw, const float* __restrict__ cb,
                      float* __restrict__ out){
  __shared__ float vsh[4];
  int tid = threadIdx.x;
  if (tid < 4){
    int ch = tid & 1, which = tid >> 1;   // which: 0=var1, 1=var2
    float s = 0.f, q = 0.f;
    for (int seg = 0; seg < 32; ++seg){
      const float* p = part + (size_t)(seg*2+ch)*4 + which*2;
      s += p[0]; q += p[1];
    }
    float n = which ? 196608.f : 65536.f;
    vsh[tid] = (q - s*s/n) / (n - 1.f);
  }
  __syncthreads();
  int idx = blockIdx.x*256 + tid;   // 64*1024
  int n = idx & 1023, b = idx >> 10;
  float c0 = cptr[0];
  float v10 = vsh[0], v11 = vsh[1], v20 = vsh[2], v21 = vsh[3];
  size_t i0 = (size_t)(b*2+0)*1024 + n, i1 = (size_t)(b*2+1)*1024 + n;
  float p0 = (H[i0]*v10*c0 + rH[i0]*v20) / (v10 + v20*c0);
  float p1 = (H[i1]*v11*c0 + rH[i1]*v21) / (v11 + v21*c0);
  float* ob = out + (size_t)b*24*1024 + n;
  #pragma unroll
  for (int o = 0; o < 24; ++o)
    ob[(size_t)o*1024] = p0*cw[o*2+0] + p1*cw[o*2+1] + cb[o];
}

// ---------------- launch ----------------
extern "C" void kernel_launch(void* const* d_in, const int* in_sizes, int n_in,
                              void* d_out, int out_size, void* d_ws, size_t ws_size,
                              hipStream_t stream) {
  const float* inputs = (const float*)d_in[0];
  const float* adj    = (const float*)d_in[1];
  const float* gcw    = (const float*)d_in[2];
  const float* Wf  = (const float*)d_in[3];  const float* bf_ = (const float*)d_in[4];
  const float* Wi  = (const float*)d_in[5];  const float* bi_ = (const float*)d_in[6];
  const float* Wo  = (const float*)d_in[7];  const float* bo_ = (const float*)d_in[8];
  const float* Wc  = (const float*)d_in[9];  const float* bc_ = (const float*)d_in[10];
  const float* rWf = (const float*)d_in[11]; const float* rbf = (const float*)d_in[12];
  const float* rWi = (const float*)d_in[13]; const float* rbi = (const float*)d_in[14];
  const float* rWo = (const float*)d_in[15]; const float* rbo = (const float*)d_in[16];
  const float* rWc = (const float*)d_in[17]; const float* rbc = (const float*)d_in[18];
  const float* nw     = (const float*)d_in[19];
  const float* cscal  = (const float*)d_in[20];
  const float* convw  = (const float*)d_in[21];
  const float* convb  = (const float*)d_in[22];
  float* out = (float*)d_out;

  char* cur = (char*)d_ws;
  auto alloc = [&](size_t bytes) -> void* {
    void* p = cur; cur += (bytes + 255) & ~(size_t)255; return p;
  };
  u16*   Xb     = (u16*)  alloc((size_t)LS*BC*NN*2);      // 6 MB
  float* csum   = (float*)alloc((size_t)64*1024*4);
  u16*   anormT = (u16*)  alloc((size_t)NN*NN*2);         // 2 MB
  u16*   Apowb  = (u16*)  alloc((size_t)3*NN*NN*2);       // 6 MB
  float* nbrv   = (float*)alloc(1024*4);
  u16*   effb   = (u16*)  alloc((size_t)3*NN*NN*2);       // 6 MB
  u16*   effbT  = (u16*)  alloc((size_t)3*NN*NN*2);       // 6 MB
  u16*   Wgxb   = (u16*)  alloc((size_t)4096*3072*2);     // 24 MB
  u16*   WgHp   = (u16*)  alloc((size_t)4096*1024*2);     // 8 MB
  u16*   rWgHp  = (u16*)  alloc((size_t)4096*1024*2);     // 8 MB
  u16*   Bcat   = (u16*)  alloc((size_t)8192*1024*2);     // 16 MB: [Cw; rWgx]
  float* bgcat  = (float*)alloc(8192*4);
  u16*   gclb   = (u16*)  alloc((size_t)BC*3072*2);
  u16*   prebuf = (u16*)  alloc((size_t)3072*8192*2);     // 48 MB bf16
  char*  zbase  = cur;
  u16*   Hb2    = (u16*)  alloc((size_t)2*BC*NN*2);
  u16*   rHb2   = (u16*)  alloc((size_t)2*BC*NN*2);
  float* Cs     = (float*)alloc((size_t)BC*NN*4);
  float* rCs    = (float*)alloc((size_t)BC*NN*4);
  size_t zlen   = (size_t)(cur - zbase);
  float* Hfv    = (float*)alloc((size_t)BC*NN*4);
  float* rHfv   = (float*)alloc((size_t)BC*NN*4);
  float* part   = (float*)alloc(64*4*4);

  u16* A1b = Apowb;
  u16* A2b = Apowb + (size_t)NN*NN;
  u16* A3b = Apowb + (size_t)2*NN*NN;
  u16* Cwb   = Bcat;                       // rows 0..4095
  u16* rWgxb = Bcat + (size_t)4096*1024;   // rows 4096..8191

  // fused preprocessing
  k_prep<<<208 + (2097152+1048576)/256, 256, 0, stream>>>(
      inputs, adj, Wf, Wi, Wo, Wc, rWf, rWi, rWo, rWc,
      bf_, bi_, bo_, bc_, rbf, rbi, rbo, rbc,
      Xb, csum, Wgxb, WgHp, rWgxb, rWgHp, bgcat);
  hipMemsetAsync(zbase, 0, zlen, stream);
  dim3 g16(16, 16);
  k_anormT<<<g16, 256, 0, stream>>>(adj, csum, A1b, anormT);
  // adjacency powers, 64^2 tiles BK=128
  k_mfma64<<<g16, 256, 0, stream>>>(A1b, anormT, 1024, 1, 0, A2b, 1024);
  k_mfma64<<<g16, 256, 0, stream>>>(A2b, anormT, 1024, 1, 0, A3b, 1024);
  // merged nbr + effT
  k_nbreff<<<1792, 256, 0, stream>>>(A3b, nw, nbrv, Apowb, gcw, effb, effbT);

  // Cw = Wgx @ eff (4096x1024, K=3072), XCD-swizzled (grid (16,64))
  dim3 gcwg(16, 64);
  k_mfma64<<<gcwg, 256, 0, stream>>>(Wgxb, effbT, 3072, 0, 1, Cwb, 1024);
  // pre slice 0 only (256 blocks of 64x64 tiles)
  k_pre0<<<256, 256, 0, stream>>>(Xb, Bcat, bgcat, prebuf);
  // last-step gc (for var only)
  dim3 ggcl(48, 2);
  k_mfma64<<<ggcl, 256, 0, stream>>>(Xb + (size_t)(LS-1)*BC*NN, effb, 1024, 0, 0, gclb, 3072);

  // 24 fused steps; step t also computes pre-slice t+1 on 256 matched-grain blocks
  for (int t = 0; t < LS; ++t){
    int tn = (t+1 < LS) ? t+1 : t;
    k_step<<<768, 256, 0, stream>>>(WgHp, rWgHp,
        prebuf + (size_t)t*BC*8192,
        Xb + (size_t)tn*BC*NN, Bcat, bgcat,
        prebuf + (size_t)tn*BC*8192, (t+1 < LS) ? 1 : 0,
        nbrv, Hb2, rHb2, Cs, rCs, Hfv, rHfv, t & 1, t == LS-1);
  }

  k_var1<<<64, 256, 0, stream>>>(Xb + (size_t)(LS-1)*BC*NN, gclb, part);
  k_out<<<(64*1024)/256, 256, 0, stream>>>(Hfv, rHfv, part, cscal, convw, convb, out);
}

// Round 15
// 505.390 us; speedup vs baseline: 1.0348x; 1.0348x over previous
//
#include <hip/hip_runtime.h>
#include <cmath>

#define NN 1024
#define BC 128
#define LS 24

typedef unsigned short u16;
typedef __attribute__((ext_vector_type(4))) float f32x4;
typedef __attribute__((ext_vector_type(8))) short bf16x8;
typedef __attribute__((ext_vector_type(8))) unsigned short u16x8;

typedef __attribute__((address_space(1))) const void* as1cv;
typedef __attribute__((address_space(3))) void* as3v;

#define GLD16(gp, lp) __builtin_amdgcn_global_load_lds((as1cv)(gp), (as3v)(lp), 16, 0, 0)

__device__ __forceinline__ float sigf(float x){ return 1.0f/(1.0f+expf(-x)); }

__device__ __forceinline__ u16 f2b(float x){
  union { float f; unsigned u; } v; v.f = x;
  unsigned r = v.u + 0x7FFFu + ((v.u >> 16) & 1u);
  return (u16)(r >> 16);
}
__device__ __forceinline__ float b2f(u16 b){
  union { unsigned u; float f; } v; v.u = ((unsigned)b) << 16;
  return v.f;
}

// ---------------- fused preprocessing ----------------
// blocks [0,512): transpose; [512,576): colsum1; [576,592): packbias; [592,...): pack x8
__global__ void k_prep(const float* __restrict__ inputs, const float* __restrict__ adj,
                       const float* __restrict__ Wf, const float* __restrict__ Wi,
                       const float* __restrict__ Wo, const float* __restrict__ Wc,
                       const float* __restrict__ rWf, const float* __restrict__ rWi,
                       const float* __restrict__ rWo, const float* __restrict__ rWc,
                       const float* __restrict__ bf_, const float* __restrict__ bi_,
                       const float* __restrict__ bo_, const float* __restrict__ bc_,
                       const float* __restrict__ rbf, const float* __restrict__ rbi,
                       const float* __restrict__ rbo, const float* __restrict__ rbc,
                       u16* __restrict__ Xb, float* __restrict__ csum,
                       u16* __restrict__ Wgxb, u16* __restrict__ WgHp,
                       u16* __restrict__ rWgxb, u16* __restrict__ rWgHp,
                       float* __restrict__ bgcat){
  int b = blockIdx.x, tid = threadIdx.x;
  if (b < 512){
    int idx = b*256 + tid;                       // BC*NN
    const float4* p = (const float4*)(inputs + (size_t)idx*LS);
    float v[LS];
    #pragma unroll
    for (int q = 0; q < 6; ++q){
      float4 f = p[q];
      v[q*4]=f.x; v[q*4+1]=f.y; v[q*4+2]=f.z; v[q*4+3]=f.w;
    }
    #pragma unroll
    for (int t = 0; t < LS; ++t)
      Xb[(size_t)t*BC*NN + idx] = f2b(v[t]);
  } else if (b < 576){
    int bb = b - 512;
    for (int j = tid; j < 1024; j += 256){
      float s = 0.f;
      for (int i = 0; i < 16; ++i) s += adj[(size_t)(bb*16+i)*1024 + j];
      csum[(size_t)bb*1024 + j] = s;
    }
  } else if (b < 592){
    int idx = (b-576)*256 + tid;                 // 4096
    int seg = idx >> 10, j = idx & 1023;
    bgcat[idx]      = (seg==0?bf_: seg==1?bi_: seg==2?bo_:bc_)[j];
    bgcat[4096+idx] = (seg==0?rbf: seg==1?rbi: seg==2?rbo:rbc)[j];
  } else {
    int idx = (b-592)*256 + tid;                 // 8-element groups
    if (idx < 2097152){                          // main W: 4096 rows x 512 groups
      int kg = idx & 511, r = idx >> 9;
      int seg = r >> 10, j = r & 1023;
      const float* W = (seg==0?Wf: seg==1?Wi: seg==2?Wo:Wc) + (size_t)j*4096 + kg*8;
      float4 a = *(const float4*)W;
      float4 c = *(const float4*)(W + 4);
      u16x8 o = { f2b(a.x), f2b(a.y), f2b(a.z), f2b(a.w),
                  f2b(c.x), f2b(c.y), f2b(c.z), f2b(c.w) };
      if (kg < 384) *(u16x8*)(Wgxb + (size_t)r*3072 + kg*8) = o;
      else {
        int p = (j>>3)*32 + seg*8 + (j&7);
        *(u16x8*)(WgHp + (size_t)p*1024 + (kg*8 - 3072)) = o;
      }
    } else {
      int g2 = idx - 2097152;                    // rW: 4096 rows x 256 groups
      int kg = g2 & 255, r = g2 >> 8;
      int seg = r >> 10, j = r & 1023;
      const float* W = (seg==0?rWf: seg==1?rWi: seg==2?rWo:rWc) + (size_t)j*2048 + kg*8;
      float4 a = *(const float4*)W;
      float4 c = *(const float4*)(W + 4);
      u16x8 o = { f2b(a.x), f2b(a.y), f2b(a.z), f2b(a.w),
                  f2b(c.x), f2b(c.y), f2b(c.z), f2b(c.w) };
      if (kg < 128) *(u16x8*)(rWgxb + (size_t)r*1024 + kg*8) = o;
      else {
        int p = (j>>3)*32 + seg*8 + (j&7);
        *(u16x8*)(rWgHp + (size_t)p*1024 + (kg*8 - 1024)) = o;
      }
    }
  }
}

__global__ void k_colsum2(const float* __restrict__ part, float* __restrict__ tmp){
  int j = blockIdx.x*256 + threadIdx.x;
  float s = 0.f;
  for (int b = 0; b < 64; ++b) s += part[(size_t)b*1024 + j];
  tmp[j] = (s == 0.f) ? 1e-5f : s;
}

// fused: A1b = bf16(min(tmp[i]*adj,1)); anormT = bf16(tmp[i]*adj)^T
__global__ void k_anormT(const float* __restrict__ adj, const float* __restrict__ tmp,
                         u16* __restrict__ A1b, u16* __restrict__ anormT){
  __shared__ u16 t[64][65];
  int bi = blockIdx.y*64, bj = blockIdx.x*64;
  for (int e = threadIdx.x; e < 4096; e += 256){
    int r = e >> 6, cc = e & 63;
    float v = tmp[bi+r]*adj[(size_t)(bi+r)*1024 + bj+cc];
    A1b[(size_t)(bi+r)*1024 + bj+cc] = f2b(fminf(v, 1.f));
    t[r][cc] = f2b(v);
  }
  __syncthreads();
  for (int e = threadIdx.x; e < 4096; e += 256){
    int r = e >> 6, cc = e & 63;
    anormT[(size_t)(bj+r)*1024 + bi+cc] = t[cc][r];
  }
}

__global__ void k_nbr(const u16* __restrict__ A3b, const float* __restrict__ nw,
                      float* __restrict__ nbr){
  __shared__ float red[256];
  int row = blockIdx.x;
  float s = 0.f;
  for (int j = threadIdx.x; j < 1024; j += 256)
    s += b2f(A3b[(size_t)row*1024 + j])*nw[j];
  red[threadIdx.x] = s; __syncthreads();
  for (int st = 128; st > 0; st >>= 1){
    if (threadIdx.x < st) red[threadIdx.x] += red[threadIdx.x+st];
    __syncthreads();
  }
  if (threadIdx.x == 0) nbr[row] = red[0];
}

__global__ void k_effT(const u16* __restrict__ Ap, const float* __restrict__ gcw,
                       u16* __restrict__ effb, u16* __restrict__ effbT){
  __shared__ u16 t[64][65];
  int bi = blockIdx.y*64, bj = blockIdx.x*64;   // bi over 3072, bj over 1024
  for (int e = threadIdx.x; e < 4096; e += 256){
    int r = e >> 6, cc = e & 63;
    size_t idx = (size_t)(bi+r)*1024 + bj+cc;
    u16 v = f2b(b2f(Ap[idx]) * gcw[idx]);
    effb[idx] = v;
    t[r][cc] = v;
  }
  __syncthreads();
  for (int e = threadIdx.x; e < 4096; e += 256){
    int r = e >> 6, cc = e & 63;
    effbT[(size_t)(bj+r)*3072 + bi+cc] = t[cc][r];
  }
}

// ---------------- 64x64 pre tile (K=1024, BK=128), shared by prologue and k_step ----------------
// g in [0,256): rh = g>>7 (64-row half of slice), cp = g&127 (64-col panel of 8192)
__device__ __forceinline__ void pre_tile64(int g, const u16* __restrict__ Xs,
                                           const u16* __restrict__ Bcat,
                                           const float* __restrict__ bgcat,
                                           u16* __restrict__ outs, u16* lds)
{
  u16* ldsA = lds;            // 64*128
  u16* ldsB = lds + 8192;     // 64*128
  const int tid  = threadIdx.x;
  const int lane = tid & 63;
  const int w    = tid >> 6;
  const int wr   = (w >> 1) * 32;
  const int wc   = (w & 1) * 32;
  const int rh = g >> 7, cp = g & 127;
  const u16* A = Xs + (size_t)rh*64*1024;
  const u16* B = Bcat + (size_t)cp*64*1024;
  f32x4 acc[2][2] = {};

  const int r4  = lane >> 4;
  const int g16 = lane & 15;
  for (int k0 = 0; k0 < 1024; k0 += 128){
    #pragma unroll
    for (int c = 0; c < 4; ++c){
      int rowb = w*16 + c*4;
      int row = rowb + r4;
      int srcg = (g16 & 8) | ((g16 & 7) ^ (row & 7));
      GLD16(A + (size_t)row*1024 + k0 + srcg*8, &ldsA[rowb*128]);
      GLD16(B + (size_t)row*1024 + k0 + srcg*8, &ldsB[rowb*128]);
    }
    __syncthreads();
    #pragma unroll
    for (int kk = 0; kk < 4; ++kk){
      int idx = kk*4 + (lane >> 4);
      bf16x8 af[2], bfr[2];
      #pragma unroll
      for (int mi = 0; mi < 2; ++mi){
        int row = wr + mi*16 + (lane & 15);
        int pa = (idx & 8) | ((idx & 7) ^ (row & 7));
        af[mi] = *(const bf16x8*)&ldsA[row*128 + pa*8];
      }
      #pragma unroll
      for (int ni = 0; ni < 2; ++ni){
        int row = wc + ni*16 + (lane & 15);
        int pb = (idx & 8) | ((idx & 7) ^ (row & 7));
        bfr[ni] = *(const bf16x8*)&ldsB[row*128 + pb*8];
      }
      #pragma unroll
      for (int mi = 0; mi < 2; ++mi)
        #pragma unroll
        for (int ni = 0; ni < 2; ++ni)
          acc[mi][ni] = __builtin_amdgcn_mfma_f32_16x16x32_bf16(af[mi], bfr[ni], acc[mi][ni], 0, 0, 0);
    }
    __syncthreads();
  }
  #pragma unroll
  for (int mi = 0; mi < 2; ++mi){
    #pragma unroll
    for (int ni = 0; ni < 2; ++ni){
      int col = cp*64 + wc + ni*16 + (lane & 15);
      float bv = bgcat[col];
      #pragma unroll
      for (int q = 0; q < 4; ++q){
        int row = rh*64 + wr + mi*16 + (lane >> 4)*4 + q;
        outs[(size_t)row*8192 + col] = f2b(acc[mi][ni][q] + bv);
      }
    }
  }
}

// prologue: pre slice 0 (256 blocks)
__global__ __launch_bounds__(256) void k_pre0(
    const u16* __restrict__ Xs, const u16* __restrict__ Bcat,
    const float* __restrict__ bgcat, u16* __restrict__ outs)
{
  __shared__ u16 lds[16384];
  pre_tile64(blockIdx.x, Xs, Bcat, bgcat, outs, lds);
}

// ---------------- 64x64-tile NT GEMM, BK=128 (32 KB LDS) ----------------
__global__ __launch_bounds__(256) void k_mfma64(
    const u16* __restrict__ Ag, const u16* __restrict__ Bg, int K,
    int clamp1, int swz, u16* __restrict__ outb, int ldc)
{
  __shared__ u16 ldsA[64*128];   // 16 KB
  __shared__ u16 ldsB[64*128];   // 16 KB
  const int tid  = threadIdx.x;
  const int lane = tid & 63;
  const int w    = tid >> 6;
  const int wr   = (w >> 1) * 32;
  const int wc   = (w & 1) * 32;
  int bx = blockIdx.x, by = blockIdx.y;
  if (swz){  // valid for grid (16,64): each XCD owns an 8-panel A-stripe (3 MB, L2-fit)
    int id = by*16 + bx;
    by = (id & 7)*8 + ((id >> 3) & 7);   // [0,64)
    bx = id >> 6;                        // [0,16)
  }
  const u16* A = Ag + (size_t)by*64*K;
  const u16* B = Bg + (size_t)bx*64*K;
  f32x4 acc[2][2] = {};

  const int r4  = lane >> 4;
  const int g16 = lane & 15;
  for (int k0 = 0; k0 < K; k0 += 128){
    #pragma unroll
    for (int c = 0; c < 4; ++c){
      int rowb = w*16 + c*4;
      int row = rowb + r4;
      int srcg = (g16 & 8) | ((g16 & 7) ^ (row & 7));
      GLD16(A + (size_t)row*K + k0 + srcg*8, &ldsA[rowb*128]);
      GLD16(B + (size_t)row*K + k0 + srcg*8, &ldsB[rowb*128]);
    }
    __syncthreads();
    #pragma unroll
    for (int kk = 0; kk < 4; ++kk){
      int idx = kk*4 + (lane >> 4);
      bf16x8 af[2], bfr[2];
      #pragma unroll
      for (int mi = 0; mi < 2; ++mi){
        int row = wr + mi*16 + (lane & 15);
        int pa = (idx & 8) | ((idx & 7) ^ (row & 7));
        af[mi] = *(const bf16x8*)&ldsA[row*128 + pa*8];
      }
      #pragma unroll
      for (int ni = 0; ni < 2; ++ni){
        int row = wc + ni*16 + (lane & 15);
        int pb = (idx & 8) | ((idx & 7) ^ (row & 7));
        bfr[ni] = *(const bf16x8*)&ldsB[row*128 + pb*8];
      }
      #pragma unroll
      for (int mi = 0; mi < 2; ++mi)
        #pragma unroll
        for (int ni = 0; ni < 2; ++ni)
          acc[mi][ni] = __builtin_amdgcn_mfma_f32_16x16x32_bf16(af[mi], bfr[ni], acc[mi][ni], 0, 0, 0);
    }
    __syncthreads();
  }
  #pragma unroll
  for (int mi = 0; mi < 2; ++mi){
    #pragma unroll
    for (int ni = 0; ni < 2; ++ni){
      int col = bx*64 + wc + ni*16 + (lane & 15);
      #pragma unroll
      for (int q = 0; q < 4; ++q){
        int row = by*64 + wr + mi*16 + (lane >> 4)*4 + q;
        float v = acc[mi][ni][q];
        if (clamp1) v = fminf(v, 1.f);
        outb[(size_t)row*ldc + col] = f2b(v);
      }
    }
  }
}

// ---------------- fused per-step kernel: 512 LSTM blocks + 256 pre-slice(t+1) blocks ----------
// LSTM (bid<512): job = bid>>8; rem = bid&255; s = rem>>1; r0 = (rem&1)*64.
// GEMM M=64, N=32, K=1024, BK=128 double-buffered counted-vmcnt (round-10 verified).
// Pre (bid>=512): 64x64 tile g = bid-512 of pre-slice t+1 (grain ~5us < LSTM ~9us).
__global__ __launch_bounds__(256) void k_step(
    const u16* __restrict__ WgHp, const u16* __restrict__ rWgHp,
    const u16* __restrict__ pre_t,           // [BC][8192] bf16; job*4096 col offset
    const u16* __restrict__ Xb_next, const u16* __restrict__ Bcat,
    const float* __restrict__ bgcat, u16* __restrict__ pre_next, int do_pre,
    const float* __restrict__ nbrv,
    u16* __restrict__ Hb2, u16* __restrict__ rHb2,
    float* __restrict__ Cs, float* __restrict__ rCs,
    float* __restrict__ Hf, float* __restrict__ rHf,
    int ph, int last)
{
  __shared__ u16 lds[24576];   // 48 KB (LSTM); pre branch uses first 32 KB

  const int tid  = threadIdx.x;
  const int lane = tid & 63;
  const int w    = tid >> 6;          // 0..3
  const int bid  = blockIdx.x;

  if (bid >= 512){
    if (do_pre) pre_tile64(bid - 512, Xb_next, Bcat, bgcat, pre_next, lds);
    return;
  }

  u16* ldsA0 = lds;              // [2][64*128]
  u16* ldsB0 = lds + 16384;      // [2][32*128]

  const int job  = bid >> 8;
  const int rem  = bid & 255;
  const int s    = rem >> 1;
  const int r0   = (rem & 1) * 64;

  const u16* Bp   = (job ? rWgHp : WgHp) + (size_t)s*32*1024;
  const u16* Ab   = (job ? rHb2 : Hb2) + (size_t)ph*BC*NN + (size_t)r0*NN;
  const u16* pret = pre_t + (size_t)job*4096;
  u16* Hnext  = (job ? rHb2 : Hb2) + (size_t)(ph^1)*BC*NN;
  float* Csb  = job ? rCs : Cs;
  float* Hfin = job ? rHf : Hf;

  const int r4  = lane >> 4;           // 0..3 row offset within 1KB issue
  const int g16 = lane & 15;           // 16B group within 256B row

  // 6 GLD16 per wave per chunk: 4 for A (16 rows), 2 for B (8 rows)
  auto STAGE = [&](int ck, int buf){
    int k0 = ck*128;
    #pragma unroll
    for (int c = 0; c < 4; ++c){
      int rowb = w*16 + c*4;
      int row = rowb + r4;
      int srcg = (g16 & 8) | ((g16 & 7) ^ (row & 7));
      GLD16(Ab + (size_t)row*1024 + k0 + srcg*8, &ldsA0[buf*8192 + rowb*128]);
    }
    #pragma unroll
    for (int c = 0; c < 2; ++c){
      int rowb = w*8 + c*4;
      int row = rowb + r4;
      int srcg = (g16 & 8) | ((g16 & 7) ^ (row & 7));
      GLD16(Bp + (size_t)row*1024 + k0 + srcg*8, &ldsB0[buf*4096 + rowb*128]);
    }
  };

  f32x4 acc[2] = {};
  STAGE(0, 0);
  #pragma unroll
  for (int t = 0; t < 8; ++t){
    const int cur = t & 1;
    if (t < 7){
      STAGE(t+1, cur^1);
      asm volatile("s_waitcnt vmcnt(6)" ::: "memory");   // cur's 6 oldest done; next's stay in flight
    } else {
      asm volatile("s_waitcnt vmcnt(0)" ::: "memory");
    }
    __builtin_amdgcn_sched_barrier(0);
    __builtin_amdgcn_s_barrier();
    #pragma unroll
    for (int kk = 0; kk < 4; ++kk){
      int idx = kk*4 + (lane >> 4);
      int rowa = w*16 + (lane & 15);
      int pa = (idx & 8) | ((idx & 7) ^ (rowa & 7));
      bf16x8 af = *(const bf16x8*)&ldsA0[cur*8192 + rowa*128 + pa*8];
      #pragma unroll
      for (int ni = 0; ni < 2; ++ni){
        int rowb2 = ni*16 + (lane & 15);
        int pb = (idx & 8) | ((idx & 7) ^ (rowb2 & 7));
        bf16x8 bv = *(const bf16x8*)&ldsB0[cur*4096 + rowb2*128 + pb*8];
        acc[ni] = __builtin_amdgcn_mfma_f32_16x16x32_bf16(af, bv, acc[ni], 0, 0, 0);
      }
    }
    __builtin_amdgcn_sched_barrier(0);
    __builtin_amdgcn_s_barrier();   // protect buf[cur] before chunk t+1 stages into it
  }

  // epilogue: + pre, gates via shfl_xor(8) (round-4/9/10/13 verified mapping)
  #pragma unroll
  for (int ni = 0; ni < 2; ++ni){
    int pcol = ni*16 + (lane & 15);
    int gcol = (pcol >> 3)*1024 + s*8 + (pcol & 7);
    #pragma unroll
    for (int q = 0; q < 4; ++q){
      int row = r0 + w*16 + (lane >> 4)*4 + q;
      acc[ni][q] += b2f(pret[(size_t)row*8192 + gcol]);
    }
  }
  const bool act = (lane & 15) < 8;
  const int  c   = lane & 7;
  const int  col = s*8 + c;
  float fac = 1.f;
  if (!job && act) fac = nbrv[col];
  #pragma unroll
  for (int q = 0; q < 4; ++q){
    float a0 = acc[0][q], a1 = acc[1][q];
    float p1 = __shfl_xor(a0, 8);   // seg1 (i-gate)
    float p3 = __shfl_xor(a1, 8);   // seg3 (Ct)
    if (act){
      int row = r0 + w*16 + (lane >> 4)*4 + q;
      float fg = sigf(a0), ig = sigf(p1), og = sigf(a1), ct = tanhf(p3);
      size_t cidx = (size_t)row*NN + col;
      float cs = fg*Csb[cidx]*fac + ig*ct;
      Csb[cidx] = cs;
      float h = og*tanhf(cs);
      Hnext[cidx] = f2b(h);
      if (last) Hfin[cidx] = h;
    }
  }
}

// ---------------- last-step statistics ----------------
__global__ void k_var1(const u16* __restrict__ Xl, const u16* __restrict__ gcl,
                       float* __restrict__ part){
  int ch = blockIdx.x & 1, seg = blockIdx.x >> 1;   // 64 blocks
  int tid = threadIdx.x;
  float s1=0.f,q1=0.f,s2=0.f,q2=0.f;
  for (int bb = 0; bb < 2; ++bb){
    int row = (seg*2+bb)*2 + ch;
    const u16* xr = Xl + (size_t)row*1024;
    for (int n = tid; n < 1024; n += 256){ float v = b2f(xr[n]); s1 += v; q1 += v*v; }
    const u16* gr = gcl + (size_t)row*3072;
    for (int n = tid; n < 3072; n += 256){ float v = b2f(gr[n]); s2 += v; q2 += v*v; }
  }
  __shared__ float red[256][4];
  red[tid][0]=s1; red[tid][1]=q1; red[tid][2]=s2; red[tid][3]=q2;
  __syncthreads();
  for (int st = 128; st > 0; st >>= 1){
    if (tid < st){ for (int z = 0; z < 4; ++z) red[tid][z] += red[tid+st][z]; }
    __syncthreads();
  }
  if (tid == 0){ for (int z = 0; z < 4; ++z) part[(size_t)blockIdx.x*4 + z] = red[0][z]; }
}

// fused var2 + pred + conv: one thread per (b,n), 256 blocks
__global__ void k_out(const float* __restrict__ H, const float* __restrict__ rH,
                      const float* __restrict__ part, const float* __restrict__ cptr,
                      const float* __restrict__ cw, const float* __restrict__ cb,
                      float* __restrict__ out){
  __shared__ float vsh[4];
  int tid = threadIdx.x;
  if (tid < 4){
    int ch = tid & 1, which = tid >> 1;   // which: 0=var1, 1=var2
    float s = 0.f, q = 0.f;
    for (int seg = 0; seg < 32; ++seg){
      const float* p = part + (size_t)(seg*2+ch)*4 + which*2;
      s += p[0]; q += p[1];
    }
    float n = which ? 196608.f : 65536.f;
    vsh[tid] = (q - s*s/n) / (n - 1.f);
  }
  __syncthreads();
  int idx = blockIdx.x*256 + tid;   // 64*1024
  int n = idx & 1023, b = idx >> 10;
  float c0 = cptr[0];
  float v10 = vsh[0], v11 = vsh[1], v20 = vsh[2], v21 = vsh[3];
  size_t i0 = (size_t)(b*2+0)*1024 + n, i1 = (size_t)(b*2+1)*1024 + n;
  float p0 = (H[i0]*v10*c0 + rH[i0]*v20) / (v10 + v20*c0);
  float p1 = (H[i1]*v11*c0 + rH[i1]*v21) / (v11 + v21*c0);
  float* ob = out + (size_t)b*24*1024 + n;
  #pragma unroll
  for (int o = 0; o < 24; ++o)
    ob[(size_t)o*1024] = p0*cw[o*2+0] + p1*cw[o*2+1] + cb[o];
}

// ---------------- launch ----------------
extern "C" void kernel_launch(void* const* d_in, const int* in_sizes, int n_in,
                              void* d_out, int out_size, void* d_ws, size_t ws_size,
                              hipStream_t stream) {
  const float* inputs = (const float*)d_in[0];
  const float* adj    = (const float*)d_in[1];
  const float* gcw    = (const float*)d_in[2];
  const float* Wf  = (const float*)d_in[3];  const float* bf_ = (const float*)d_in[4];
  const float* Wi  = (const float*)d_in[5];  const float* bi_ = (const float*)d_in[6];
  const float* Wo  = (const float*)d_in[7];  const float* bo_ = (const float*)d_in[8];
  const float* Wc  = (const float*)d_in[9];  const float* bc_ = (const float*)d_in[10];
  const float* rWf = (const float*)d_in[11]; const float* rbf = (const float*)d_in[12];
  const float* rWi = (const float*)d_in[13]; const float* rbi = (const float*)d_in[14];
  const float* rWo = (const float*)d_in[15]; const float* rbo = (const float*)d_in[16];
  const float* rWc = (const float*)d_in[17]; const float* rbc = (const float*)d_in[18];
  const float* nw     = (const float*)d_in[19];
  const float* cscal  = (const float*)d_in[20];
  const float* convw  = (const float*)d_in[21];
  const float* convb  = (const float*)d_in[22];
  float* out = (float*)d_out;

  char* cur = (char*)d_ws;
  auto alloc = [&](size_t bytes) -> void* {
    void* p = cur; cur += (bytes + 255) & ~(size_t)255; return p;
  };
  u16*   Xb     = (u16*)  alloc((size_t)LS*BC*NN*2);      // 6 MB
  float* csum   = (float*)alloc((size_t)64*1024*4);
  float* tmpv   = (float*)alloc(1024*4);
  u16*   anormT = (u16*)  alloc((size_t)NN*NN*2);         // 2 MB
  u16*   Apowb  = (u16*)  alloc((size_t)3*NN*NN*2);       // 6 MB
  float* nbrv   = (float*)alloc(1024*4);
  u16*   effb   = (u16*)  alloc((size_t)3*NN*NN*2);       // 6 MB
  u16*   effbT  = (u16*)  alloc((size_t)3*NN*NN*2);       // 6 MB
  u16*   Wgxb   = (u16*)  alloc((size_t)4096*3072*2);     // 24 MB
  u16*   WgHp   = (u16*)  alloc((size_t)4096*1024*2);     // 8 MB
  u16*   rWgHp  = (u16*)  alloc((size_t)4096*1024*2);     // 8 MB
  u16*   Bcat   = (u16*)  alloc((size_t)8192*1024*2);     // 16 MB: [Cw; rWgx]
  float* bgcat  = (float*)alloc(8192*4);
  u16*   gclb   = (u16*)  alloc((size_t)BC*3072*2);
  u16*   prebuf = (u16*)  alloc((size_t)3072*8192*2);     // 48 MB bf16
  char*  zbase  = cur;
  u16*   Hb2    = (u16*)  alloc((size_t)2*BC*NN*2);
  u16*   rHb2   = (u16*)  alloc((size_t)2*BC*NN*2);
  float* Cs     = (float*)alloc((size_t)BC*NN*4);
  float* rCs    = (float*)alloc((size_t)BC*NN*4);
  size_t zlen   = (size_t)(cur - zbase);
  float* Hfv    = (float*)alloc((size_t)BC*NN*4);
  float* rHfv   = (float*)alloc((size_t)BC*NN*4);
  float* part   = (float*)alloc(64*4*4);

  u16* A1b = Apowb;
  u16* A2b = Apowb + (size_t)NN*NN;
  u16* A3b = Apowb + (size_t)2*NN*NN;
  u16* Cwb   = Bcat;                       // rows 0..4095
  u16* rWgxb = Bcat + (size_t)4096*1024;   // rows 4096..8191

  // fused preprocessing: transpose + colsum1 + packbias + pack (8 elems/thread)
  k_prep<<<592 + (2097152+1048576)/256, 256, 0, stream>>>(
      inputs, adj, Wf, Wi, Wo, Wc, rWf, rWi, rWo, rWc,
      bf_, bi_, bo_, bc_, rbf, rbi, rbo, rbc,
      Xb, csum, Wgxb, WgHp, rWgxb, rWgHp, bgcat);
  hipMemsetAsync(zbase, 0, zlen, stream);
  k_colsum2<<<4, 256, 0, stream>>>(csum, tmpv);
  dim3 g16(16, 16);
  k_anormT<<<g16, 256, 0, stream>>>(adj, tmpv, A1b, anormT);
  // adjacency powers, 64^2 tiles BK=128
  k_mfma64<<<g16, 256, 0, stream>>>(A1b, anormT, 1024, 1, 0, A2b, 1024);
  k_mfma64<<<g16, 256, 0, stream>>>(A2b, anormT, 1024, 1, 0, A3b, 1024);
  k_nbr<<<NN, 256, 0, stream>>>(A3b, nw, nbrv);
  dim3 geff(16, 48);
  k_effT<<<geff, 256, 0, stream>>>(Apowb, gcw, effb, effbT);

  // Cw = Wgx @ eff (4096x1024, K=3072), XCD-swizzled (grid (16,64))
  dim3 gcwg(16, 64);
  k_mfma64<<<gcwg, 256, 0, stream>>>(Wgxb, effbT, 3072, 0, 1, Cwb, 1024);
  // pre slice 0 only (256 blocks of 64x64 tiles)
  k_pre0<<<256, 256, 0, stream>>>(Xb, Bcat, bgcat, prebuf);
  // last-step gc (for var only)
  dim3 ggcl(48, 2);
  k_mfma64<<<ggcl, 256, 0, stream>>>(Xb + (size_t)(LS-1)*BC*NN, effb, 1024, 0, 0, gclb, 3072);

  // 24 fused steps; step t also computes pre-slice t+1 on 256 matched-grain blocks
  for (int t = 0; t < LS; ++t){
    int tn = (t+1 < LS) ? t+1 : t;
    k_step<<<768, 256, 0, stream>>>(WgHp, rWgHp,
        prebuf + (size_t)t*BC*8192,
        Xb + (size_t)tn*BC*NN, Bcat, bgcat,
        prebuf + (size_t)tn*BC*8192, (t+1 < LS) ? 1 : 0,
        nbrv, Hb2, rHb2, Cs, rCs, Hfv, rHfv, t & 1, t == LS-1);
  }

  k_var1<<<64, 256, 0, stream>>>(Xb + (size_t)(LS-1)*BC*NN, gclb, part);
  k_out<<<(64*1024)/256, 256, 0, stream>>>(Hfv, rHfv, part, cscal, convw, convb, out);
}